// Round 17
// baseline (198.839 us; speedup 1.0000x reference)
//
#include <hip/hip_runtime.h>
#include <hip/hip_bf16.h>
#include <stdint.h>

#define NB    32
#define CIN   64
#define HW    56
#define OHW   57
#define LL    3249
#define PATCH 256
#define NCENT 512
#define OC    128
#define NROWS (NB*LL)          // 103968
#define NROWS_PAD 104064       // 813*128
#define PL    (PATCH*LL)       // 831744

typedef __attribute__((ext_vector_type(8))) short short8;      // bf16x8 MFMA frag
typedef __attribute__((ext_vector_type(4))) float f32x4;
typedef __attribute__((ext_vector_type(4))) int   int4v;
typedef int int4u __attribute__((ext_vector_type(4), aligned(4)));
typedef float f4u __attribute__((ext_vector_type(4), aligned(4)));
typedef __attribute__((ext_vector_type(4))) unsigned short ushort4v;
typedef __attribute__((ext_vector_type(8))) unsigned short ushort8;
typedef unsigned short ushort8u __attribute__((ext_vector_type(8), aligned(2)));

// swizzle key: quad-of-rows -> chunk XOR
#define KEY3(r) ((((r) >> 2) & 3) << 3)   // element units (16B chunks)
#define KEY4(r) ((((r) >> 2) & 3) << 4)   // byte units (16B chunks)

// ---------------- ws layout ----------------
constexpr size_t OFF_C2   = 0;
constexpr size_t OFF_X2   = 4096;
constexpr size_t OFF_DENP = OFF_X2 + (size_t)NROWS_PAD*4;          // 8 partials
constexpr size_t OFF_CBF  = OFF_DENP + (size_t)8*NROWS_PAD*4;
constexpr size_t OFF_CTBF = OFF_CBF + (size_t)NCENT*PATCH*2;
constexpr size_t OFF_WBF  = OFF_CTBF + (size_t)PATCH*NCENT*2;
constexpr size_t OFF_FLAT = OFF_WBF + (size_t)OC*PATCH*2;
constexpr size_t OFF_P    = OFF_FLAT + (size_t)NROWS_PAD*PATCH*2;
constexpr size_t OFF_FBM  = OFF_P + (size_t)NROWS_PAD*NCENT*2;

__device__ __forceinline__ unsigned short f2bf(float f) {
    __hip_bfloat16 h = __float2bfloat16(f);     // RNE, hardware cvt on gfx950
    union { __hip_bfloat16 h; unsigned short u; } v; v.h = h;
    return v.u;
}
__device__ __forceinline__ float bf2f(uint16_t h) {
    union { uint32_t u; float f; } v; v.u = ((uint32_t)h) << 16;
    return v.f;
}
__device__ __forceinline__ void gload16(const void* g, void* l) {
    __builtin_amdgcn_global_load_lds(
        (const __attribute__((address_space(1))) unsigned int*)g,
        (__attribute__((address_space(3))) unsigned int*)l, 16, 0, 0);
}

// ---------------- K0a: centers -> cbf/ctbf/c2  +  weight -> wbf (merged) ----------------
__global__ __launch_bounds__(256)
void k0a_prep(const float* __restrict__ centers, const float* __restrict__ weight,
              uint16_t* __restrict__ cbf, uint16_t* __restrict__ ctbf,
              uint16_t* __restrict__ wbf, float* __restrict__ c2) {
    int bid = blockIdx.x;
    int k = threadIdx.x;           // 0..255
    if (bid < NCENT) {
        __shared__ float red[4];
        int c = bid;
        float v = centers[c*PATCH + k];
        cbf[c*PATCH + (k ^ KEY3(c))] = f2bf(v);
        ctbf[k*NCENT + (c ^ KEY3(k))] = f2bf(v);
        float s = v*v;
        s += __shfl_xor(s, 1);  s += __shfl_xor(s, 2);  s += __shfl_xor(s, 4);
        s += __shfl_xor(s, 8);  s += __shfl_xor(s, 16); s += __shfl_xor(s, 32);
        int w = threadIdx.x >> 6;
        if ((threadIdx.x & 63) == 0) red[w] = s;
        __syncthreads();
        if (threadIdx.x == 0) c2[c] = red[0] + red[1] + red[2] + red[3];
    } else {
        int o = bid - NCENT;       // 0..127 weight rows
        wbf[o*PATCH + (k ^ KEY3(o))] = f2bf(weight[o*PATCH + k]);
    }
}

// ---------------- K0b: x -> flat bf16 (swz KEY3(n)) + x2 (interior float4 fast path) ----------------
__global__ __launch_bounds__(256)
void k0b_flat(const float* __restrict__ x, uint16_t* __restrict__ flat,
              float* __restrict__ x2) {
    int tid = threadIdx.x;
    int w = tid >> 6, lane = tid & 63;
    for (int pp = 0; pp < 8; ++pp) {
        int n = blockIdx.x*32 + pp*4 + w;
        int b = n / LL;
        int rr = n - b*LL;
        int k0 = lane*4;
        int o0 = rr*PATCH + k0;
        int p = o0 / LL; int l = o0 - p*LL;
        int i = l / OHW; int j = l - i*OHW;
        float vals[4];
        {
            int cc = p >> 2, ki = (p >> 1) & 1, kj = p & 1;
            int y = i + ki - 1;
            bool fast = (n < NROWS) && ((unsigned)y < HW) &&
                        (j >= 1 - kj) && (j <= 53 - kj);
            if (fast) {
                f4u v4 = *(const f4u*)(x + ((size_t)(b*CIN + cc)*HW + y)*HW + (j + kj - 1));
                vals[0] = v4.x; vals[1] = v4.y; vals[2] = v4.z; vals[3] = v4.w;
                j += 4;
                if (j >= OHW) { j -= OHW; if (++i == OHW) { i = 0; ++p; } }
            } else {
#pragma unroll
                for (int e = 0; e < 4; ++e) {
                    float val = 0.f;
                    if (n < NROWS) {
                        int cc2 = p >> 2, ki2 = (p >> 1) & 1, kj2 = p & 1;
                        int y2 = i + ki2 - 1, xx = j + kj2 - 1;
                        if ((unsigned)y2 < HW && (unsigned)xx < HW)
                            val = x[((b*CIN + cc2)*HW + y2)*HW + xx];
                    }
                    vals[e] = val;
                    if (++j == OHW) { j = 0; if (++i == OHW) { i = 0; ++p; } }
                }
            }
        }
        float s = 0.f;
        ushort4v pk;
#pragma unroll
        for (int e = 0; e < 4; ++e) {
            pk[e] = f2bf(vals[e]);
            s += vals[e]*vals[e];
        }
        *(ushort4v*)(flat + (size_t)n*PATCH + (k0 ^ KEY3(n))) = pk;
        s += __shfl_xor(s, 1);  s += __shfl_xor(s, 2);  s += __shfl_xor(s, 4);
        s += __shfl_xor(s, 8);  s += __shfl_xor(s, 16); s += __shfl_xor(s, 32);
        if (lane == 0) x2[n] = s;
    }
}

// ---------------- K1: scores GEMM, BK=32, 32KB LDS, 4 blocks/CU, XCD-grouped swizzle ----------------
__global__ __launch_bounds__(256, 4)
void k1_scores(const uint16_t* __restrict__ flat, const uint16_t* __restrict__ cbf,
               const float* __restrict__ x2g, const float* __restrict__ c2g,
               const float* __restrict__ temp_p,
               uint16_t* __restrict__ P, float* __restrict__ denp) {
    __shared__ __align__(16) char lds[32768];   // 2 bufs x (A 8K + B 8K)
    const int tid = threadIdx.x;
    // XCD-grouping swizzle: 4 nt-sharers of one mt get ids === (mod 8) -> same XCD L2
    int id = blockIdx.x + 4*blockIdx.y;         // 0..3251
    int mt, nt;
    if (id < 3232) { mt = (id & 7) + 8*(id >> 5); nt = (id >> 3) & 3; }
    else { int t = id - 3232; mt = 808 + t % 5; nt = t / 5; }   // bijective tail (20)
    const int w = tid >> 6, lane = tid & 63;
    const int wr = w >> 1, wc = w & 1;
    const int l15 = lane & 15, l4 = lane >> 4;

    auto stage = [&](int buf, int kt) {
        const char* srcA = (const char*)flat + (size_t)(mt*128)*512 + kt*64;
        const char* srcB = (const char*)cbf + (size_t)(nt*128)*512 + kt*64;
        char* dA = lds + buf*16384;
        char* dB = dA + 8192;
#pragma unroll
        for (int i = 0; i < 2; ++i) {
            int u = (w*2 + i)*64 + lane;         // 0..511 16B-units
            int row = u >> 2, sub = u & 3;
            gload16(srcA + (size_t)row*512 + sub*16, dA + u*16);
            gload16(srcB + (size_t)row*512 + sub*16, dB + u*16);
        }
    };

    f32x4 acc[4][4];
#pragma unroll
    for (int i = 0; i < 4; ++i)
#pragma unroll
        for (int j = 0; j < 4; ++j) acc[i][j] = (f32x4)0.f;

    stage(0, 0);
    for (int kt = 0; kt < 8; ++kt) {
        __syncthreads();
        if (kt < 7) stage((kt + 1) & 1, kt + 1);
        const char* A = lds + (kt & 1)*16384;
        const char* B = A + 8192;
        short8 af[4], bfm[4];
#pragma unroll
        for (int rf = 0; rf < 4; ++rf) {
            int row = wr*64 + rf*16 + l15;
            int byte = row*64 + ((l4*16) ^ KEY4(row));
            af[rf] = *(const short8*)(A + byte);
        }
#pragma unroll
        for (int cf = 0; cf < 4; ++cf) {
            int row = wc*64 + cf*16 + l15;
            int byte = row*64 + ((l4*16) ^ KEY4(row));
            bfm[cf] = *(const short8*)(B + byte);
        }
#pragma unroll
        for (int rf = 0; rf < 4; ++rf)
#pragma unroll
            for (int cf = 0; cf < 4; ++cf)
                acc[rf][cf] = __builtin_amdgcn_mfma_f32_16x16x32_bf16(
                    af[rf], bfm[cf], acc[rf][cf], 0, 0, 0);
    }

    // epilogue: exp + den partials (fast sqrt via rsq; native exp)
    const float temp = temp_p[0];
    const float ntemp = -temp;
    float c2v[4];
#pragma unroll
    for (int cf = 0; cf < 4; ++cf)
        c2v[cf] = c2g[nt*128 + wc*64 + cf*16 + l15];

    float denacc[4][4];
#pragma unroll
    for (int rf = 0; rf < 4; ++rf) {
#pragma unroll
        for (int rr = 0; rr < 4; ++rr) {
            int n = mt*128 + wr*64 + rf*16 + l4*4 + rr;
            float x2v = x2g[n];
            float d = 0.f;
#pragma unroll
            for (int cf = 0; cf < 4; ++cf) {
                float s = x2v + c2v[cf] - 2.f*acc[rf][cf][rr];
                float sc = fmaxf(s, 1e-12f);
                float dist = sc * __frsqrt_rn(sc);     // sqrt(sc), 1 trans + 1 mul
                float pv = __expf(ntemp * dist);
                acc[rf][cf][rr] = pv;
                d += pv;
            }
            denacc[rf][rr] = d;
        }
    }
#pragma unroll
    for (int rf = 0; rf < 4; ++rf)
#pragma unroll
        for (int rr = 0; rr < 4; ++rr) {
            float v = denacc[rf][rr];
            v += __shfl_xor(v, 1); v += __shfl_xor(v, 2);
            v += __shfl_xor(v, 4); v += __shfl_xor(v, 8);
            if (l15 == 0) {
                int n = mt*128 + wr*64 + rf*16 + l4*4 + rr;
                denp[(size_t)(nt*2 + wc)*NROWS_PAD + n] = v;
            }
        }

    // bounce P through LDS (pre-swizzled KEY3(row) for K2's staging), linear store
    __syncthreads();
    uint16_t* Pl = (uint16_t*)lds;                 // 32KB = 128 x 128 bf16
#pragma unroll
    for (int rf = 0; rf < 4; ++rf)
#pragma unroll
        for (int cf = 0; cf < 4; ++cf)
#pragma unroll
            for (int rr = 0; rr < 4; ++rr) {
                int row = wr*64 + rf*16 + l4*4 + rr;
                int cl  = wc*64 + cf*16 + l15;
                Pl[row*128 + (cl ^ KEY3(row))] = (uint16_t)f2bf(acc[rf][cf][rr]);
            }
    __syncthreads();
#pragma unroll
    for (int i = 0; i < 8; ++i) {
        int c = i*256 + tid;
        int row = c >> 4, sub = c & 15;
        int4v v = *(const int4v*)((const char*)lds + c*16);
        *(int4v*)((char*)P + (size_t)(mt*128 + row)*1024 + nt*256 + sub*16) = v;
    }
}

// ---------------- K2: PV GEMM + den-merge, BK=32, 32KB LDS, 4 blocks/CU, XCD-grouped ----------------
__global__ __launch_bounds__(256, 4)
void k2_pv(const uint16_t* __restrict__ P, const uint16_t* __restrict__ ctbf,
           const uint16_t* __restrict__ flat, const float* __restrict__ denp,
           const float* __restrict__ temp_p, uint16_t* __restrict__ fbm) {
    __shared__ __align__(16) char lds[32768];   // 2 bufs x (A 8K + B 8K); reused as Tl
    const int tid = threadIdx.x;
    // XCD-grouping swizzle: 2 nt-sharers of one mt -> same XCD L2
    int id = blockIdx.x + 2*blockIdx.y;         // 0..1625
    int mt, nt;
    if (id < 1616) { mt = (id & 7) + 8*(id >> 4); nt = (id >> 3) & 1; }
    else { int t = id - 1616; mt = 808 + t % 5; nt = t / 5; }   // bijective tail (10)
    const int w = tid >> 6, lane = tid & 63;
    const int wr = w >> 1, wc = w & 1;
    const int l15 = lane & 15, l4 = lane >> 4;

    auto stage = [&](int buf, int kt) {
        const char* srcA = (const char*)P + (size_t)(mt*128)*1024 + kt*64;
        const char* srcB = (const char*)ctbf + (size_t)(nt*128)*1024 + kt*64;
        char* dA = lds + buf*16384;
        char* dB = dA + 8192;
#pragma unroll
        for (int i = 0; i < 2; ++i) {
            int u = (w*2 + i)*64 + lane;         // 0..511 16B-units
            int row = u >> 2, sub = u & 3;
            gload16(srcA + (size_t)row*1024 + sub*16, dA + u*16);
            gload16(srcB + (size_t)row*1024 + sub*16, dB + u*16);
        }
    };

    f32x4 acc[4][4];
#pragma unroll
    for (int i = 0; i < 4; ++i)
#pragma unroll
        for (int j = 0; j < 4; ++j) acc[i][j] = (f32x4)0.f;

    stage(0, 0);
    for (int kt = 0; kt < 16; ++kt) {
        __syncthreads();
        if (kt < 15) stage((kt + 1) & 1, kt + 1);
        const char* A = lds + (kt & 1)*16384;
        const char* B = A + 8192;
        short8 af[4], bfm[4];
#pragma unroll
        for (int rf = 0; rf < 4; ++rf) {
            int row = wr*64 + rf*16 + l15;
            int byte = row*64 + ((l4*16) ^ KEY4(row));
            af[rf] = *(const short8*)(A + byte);
        }
#pragma unroll
        for (int cf = 0; cf < 4; ++cf) {
            int row = wc*64 + cf*16 + l15;
            int byte = row*64 + ((l4*16) ^ KEY4(row));
            bfm[cf] = *(const short8*)(B + byte);
        }
#pragma unroll
        for (int rf = 0; rf < 4; ++rf)
#pragma unroll
            for (int cf = 0; cf < 4; ++cf)
                acc[rf][cf] = __builtin_amdgcn_mfma_f32_16x16x32_bf16(
                    af[rf], bfm[cf], acc[rf][cf], 0, 0, 0);
    }

    // den-merge preload: sum 8 partials per finalize row (hidden under the bounce)
    const float temp = temp_p[0];
    const float inv = 1.f / (temp + 1.f);
    const float tinv = temp * inv;
    float dsum[8];
#pragma unroll
    for (int i = 0; i < 8; ++i) {
        int n = mt*128 + (tid >> 4) + i*16;
        float s = 0.f;
#pragma unroll
        for (int p8 = 0; p8 < 8; ++p8) s += denp[(size_t)p8*NROWS_PAD + n];
        dsum[i] = s;
    }

    // ---- bounce acc (bf16, swizzled key row&7) to LDS
    __syncthreads();
    uint16_t* Tl = (uint16_t*)lds;               // 128 x 128 bf16 = 32KB
#pragma unroll
    for (int rf = 0; rf < 4; ++rf)
#pragma unroll
        for (int cf = 0; cf < 4; ++cf)
#pragma unroll
            for (int rr = 0; rr < 4; ++rr) {
                int row = wr*64 + rf*16 + l4*4 + rr;
                int col = wc*64 + cf*16 + l15;
                Tl[row*128 + (col ^ ((row & 7) << 3))] = (uint16_t)f2bf(acc[rf][cf][rr]);
            }
    __syncthreads();

    // ---- coalesced finalize: 8-m chunks, b128 loads/stores, incremental mask
#pragma unroll
    for (int i = 0; i < 8; ++i) {
        int ch = i*256 + tid;
        int row = ch >> 4, m0 = (ch & 15)*8;
        int n = mt*128 + row;
        if (n >= NROWS) continue;
        int m = nt*128 + m0;
        float a1 = __fdividef(tinv, dsum[i]);
        ushort8 tvv = *(const ushort8*)(Tl + row*128 + (m0 ^ ((row & 7) << 3)));
        ushort8 fl = *(const ushort8*)(flat + (size_t)n*PATCH + (m ^ KEY3(row)));
        int b = n / LL;
        int rrow = n - b*LL;
        int o = rrow*PATCH + m;
        int p = o / LL; int l = o - p*LL;
        int ii = l / OHW; int jj = l - ii*OHW;
        ushort8 outv;
#pragma unroll
        for (int e = 0; e < 8; ++e) {
            int ki = (p >> 1) & 1, kj = p & 1;
            bool bad = (ii == 0 && ki == 0) || (ii == 56 && ki == 1) ||
                       (jj == 0 && kj == 0) || (jj == 56 && kj == 1);
            float fin = a1*bf2f(tvv[e]) + bf2f(fl[e])*inv;
            outv[e] = bad ? (unsigned short)0 : f2bf(fin);
            if (++jj == OHW) { jj = 0; if (++ii == OHW) { ii = 0; ++p; } }
        }
        *(ushort8*)(fbm + (size_t)n*PATCH + m) = outv;
    }
}

// ---------------- K4: conv GEMM BK=32, 32KB LDS, 4 blocks/CU ----------------
__global__ __launch_bounds__(256, 4)
void k4_conv(const uint16_t* __restrict__ wbf, const uint16_t* __restrict__ fbm,
             const float* __restrict__ bias, float* __restrict__ out) {
    __shared__ __align__(16) char lds[32768];   // 2 bufs x (A 8K + B 8K); reused f32 bounce
    const int tid = threadIdx.x;
    const int lt = blockIdx.x;     // l-tile 0..25
    const int bb = blockIdx.y;     // batch
    const int w = tid >> 6, lane = tid & 63;
    const int wr = w >> 1, wc = w & 1;
    const int l15 = lane & 15, l4 = lane >> 4;

    auto stageA = [&](int buf, int kt) {
        const char* srcA = (const char*)wbf + kt*64;      // 32 p x 2B
        char* dA = lds + buf*16384;
#pragma unroll
        for (int i = 0; i < 2; ++i) {
            int u = i*256 + tid;                          // 512 units (128 oc x 4)
            int row = u >> 2, sub = u & 3;
            gload16(srcA + (size_t)row*512 + sub*16, dA + u*16);
        }
    };
    // B: transpose-stage fbm[p][l] -> sB[l][p] (32 p per kt, swizzle KEY3(llocal))
    auto stageB = [&](int buf, int kt) {
        uint16_t* sB = (uint16_t*)(lds + buf*16384 + 8192);
        int pl = lane & 31;
        int lh = lane >> 5;
#pragma unroll
        for (int i = 0; i < 2; ++i) {
            int l8 = i*8 + w*2 + lh;                      // 0..15
            const uint16_t* g = fbm + (size_t)bb*PL + (size_t)(kt*32 + pl)*LL + lt*128 + l8*8;
            ushort8u v = *(const ushort8u*)g;             // explicit 16B vector load
#pragma unroll
            for (int e = 0; e < 8; ++e) {
                int llocal = l8*8 + e;
                sB[llocal*32 + (pl ^ KEY3(llocal))] = v[e];
            }
        }
    };

    f32x4 acc[4][4];
#pragma unroll
    for (int i = 0; i < 4; ++i)
#pragma unroll
        for (int j = 0; j < 4; ++j) acc[i][j] = (f32x4)0.f;

    stageA(0, 0); stageB(0, 0);
    for (int kt = 0; kt < 8; ++kt) {
        __syncthreads();
        if (kt < 7) { stageA((kt + 1) & 1, kt + 1); stageB((kt + 1) & 1, kt + 1); }
        const char* A = lds + (kt & 1)*16384;
        const char* B = A + 8192;
        short8 af[4], bfm[4];
#pragma unroll
        for (int rf = 0; rf < 4; ++rf) {
            int row = wr*64 + rf*16 + l15;
            int byte = row*64 + ((l4*16) ^ KEY4(row));
            af[rf] = *(const short8*)(A + byte);
        }
#pragma unroll
        for (int cf = 0; cf < 4; ++cf) {
            int row = wc*64 + cf*16 + l15;
            int byte = row*64 + ((l4*16) ^ KEY4(row));
            bfm[cf] = *(const short8*)(B + byte);
        }
#pragma unroll
        for (int rf = 0; rf < 4; ++rf)
#pragma unroll
            for (int cf = 0; cf < 4; ++cf)
                acc[rf][cf] = __builtin_amdgcn_mfma_f32_16x16x32_bf16(
                    af[rf], bfm[cf], acc[rf][cf], 0, 0, 0);
    }

    // ---- epilogue in two 64-row halves (32KB f32 bounce each)
    float bv[4][4];
#pragma unroll
    for (int rf = 0; rf < 4; ++rf)
#pragma unroll
        for (int rr = 0; rr < 4; ++rr)
            bv[rf][rr] = bias[wr*64 + rf*16 + l4*4 + rr];

    float* Ol = (float*)lds;
    for (int half = 0; half < 2; ++half) {
        __syncthreads();
        if (wr == half) {
#pragma unroll
            for (int rf = 0; rf < 4; ++rf)
#pragma unroll
                for (int cf = 0; cf < 4; ++cf)
#pragma unroll
                    for (int rr = 0; rr < 4; ++rr) {
                        int rowl = rf*16 + l4*4 + rr;     // 0..63
                        int col = wc*64 + cf*16 + l15;
                        Ol[rowl*128 + col] = acc[rf][cf][rr] + bv[rf][rr];
                    }
        }
        __syncthreads();
        int base_oc = half*64;
        if (lt < 25) {
#pragma unroll
            for (int i = 0; i < 8; ++i) {
                int c = i*256 + tid;                      // 2048 units = 64 rows x 32
                int row = c >> 5, sub = c & 31;
                int4u v = *(const int4u*)((const char*)lds + c*16);
                *(int4u*)((char*)out + ((size_t)(bb*OC + base_oc + row)*LL + lt*128 + sub*4)*4) = v;
            }
        } else {
#pragma unroll
            for (int i = 0; i < 8; ++i) {
                int c = i*256 + tid;
                int row = c >> 5, sub = c & 31;
                const float* vp = (const float*)((const char*)lds + c*16);
#pragma unroll
                for (int e = 0; e < 4; ++e) {
                    int l = lt*128 + sub*4 + e;
                    if (l < LL) out[(size_t)(bb*OC + base_oc + row)*LL + l] = vp[e];
                }
            }
        }
    }
}

extern "C" void kernel_launch(void* const* d_in, const int* in_sizes, int n_in,
                              void* d_out, int out_size, void* d_ws, size_t ws_size,
                              hipStream_t stream) {
    const float* x       = (const float*)d_in[0];
    const float* weight  = (const float*)d_in[1];
    const float* bias    = (const float*)d_in[2];
    const float* centers = (const float*)d_in[3];
    const float* temp    = (const float*)d_in[4];
    float* out = (float*)d_out;

    char* ws = (char*)d_ws;
    float*    c2   = (float*)(ws + OFF_C2);
    float*    x2   = (float*)(ws + OFF_X2);
    float*    denp = (float*)(ws + OFF_DENP);
    uint16_t* cbf  = (uint16_t*)(ws + OFF_CBF);
    uint16_t* ctbf = (uint16_t*)(ws + OFF_CTBF);
    uint16_t* wbf  = (uint16_t*)(ws + OFF_WBF);
    uint16_t* flat = (uint16_t*)(ws + OFF_FLAT);
    uint16_t* P    = (uint16_t*)(ws + OFF_P);
    uint16_t* fbm  = (uint16_t*)(ws + OFF_FBM);

    k0a_prep<<<NCENT + OC, 256, 0, stream>>>(centers, weight, cbf, ctbf, wbf, c2);
    k0b_flat<<<NROWS_PAD/32, 256, 0, stream>>>(x, flat, x2);
    k1_scores<<<dim3(4, NROWS_PAD/128), 256, 0, stream>>>(flat, cbf, x2, c2, temp, P, denp);
    k2_pv<<<dim3(2, NROWS_PAD/128), 256, 0, stream>>>(P, ctbf, flat, denp, temp, fbm);
    k4_conv<<<dim3(26, NB), 256, 0, stream>>>(wbf, fbm, bias, out);
}

// Round 18
// 188.440 us; speedup vs baseline: 1.0552x; 1.0552x over previous
//
#include <hip/hip_runtime.h>
#include <hip/hip_bf16.h>
#include <stdint.h>

#define NB    32
#define CIN   64
#define HW    56
#define OHW   57
#define LL    3249
#define PATCH 256
#define NCENT 512
#define OC    128
#define NROWS (NB*LL)          // 103968
#define NROWS_PAD 104064       // 813*128
#define PL    (PATCH*LL)       // 831744

typedef __attribute__((ext_vector_type(8))) short short8;      // bf16x8 MFMA frag
typedef __attribute__((ext_vector_type(4))) float f32x4;
typedef __attribute__((ext_vector_type(4))) int   int4v;
typedef int int4u __attribute__((ext_vector_type(4), aligned(4)));
typedef float f4u __attribute__((ext_vector_type(4), aligned(4)));
typedef __attribute__((ext_vector_type(4))) unsigned short ushort4v;
typedef __attribute__((ext_vector_type(8))) unsigned short ushort8;
typedef unsigned short ushort8u __attribute__((ext_vector_type(8), aligned(2)));

// swizzle key: quad-of-rows -> chunk XOR
#define KEY3(r) ((((r) >> 2) & 3) << 3)   // element units (16B chunks)
#define KEY4(r) ((((r) >> 2) & 3) << 4)   // byte units (16B chunks)

// ---------------- ws layout ----------------
constexpr size_t OFF_C2   = 0;
constexpr size_t OFF_X2   = 4096;
constexpr size_t OFF_DENP = OFF_X2 + (size_t)NROWS_PAD*4;          // 8 partials
constexpr size_t OFF_DEN  = OFF_DENP + (size_t)8*NROWS_PAD*4;      // final den
constexpr size_t OFF_CBF  = OFF_DEN + (size_t)NROWS_PAD*4;
constexpr size_t OFF_CTBF = OFF_CBF + (size_t)NCENT*PATCH*2;
constexpr size_t OFF_WBF  = OFF_CTBF + (size_t)PATCH*NCENT*2;
constexpr size_t OFF_FLAT = OFF_WBF + (size_t)OC*PATCH*2;
constexpr size_t OFF_P    = OFF_FLAT + (size_t)NROWS_PAD*PATCH*2;
constexpr size_t OFF_FBM  = OFF_P + (size_t)NROWS_PAD*NCENT*2;

__device__ __forceinline__ unsigned short f2bf(float f) {
    __hip_bfloat16 h = __float2bfloat16(f);     // RNE, hardware cvt on gfx950
    union { __hip_bfloat16 h; unsigned short u; } v; v.h = h;
    return v.u;
}
__device__ __forceinline__ float bf2f(uint16_t h) {
    union { uint32_t u; float f; } v; v.u = ((uint32_t)h) << 16;
    return v.f;
}
__device__ __forceinline__ void gload16(const void* g, void* l) {
    __builtin_amdgcn_global_load_lds(
        (const __attribute__((address_space(1))) unsigned int*)g,
        (__attribute__((address_space(3))) unsigned int*)l, 16, 0, 0);
}

// ---------------- K0a: centers -> cbf/ctbf/c2  +  weight -> wbf (merged) ----------------
__global__ __launch_bounds__(256)
void k0a_prep(const float* __restrict__ centers, const float* __restrict__ weight,
              uint16_t* __restrict__ cbf, uint16_t* __restrict__ ctbf,
              uint16_t* __restrict__ wbf, float* __restrict__ c2) {
    int bid = blockIdx.x;
    int k = threadIdx.x;           // 0..255
    if (bid < NCENT) {
        __shared__ float red[4];
        int c = bid;
        float v = centers[c*PATCH + k];
        cbf[c*PATCH + (k ^ KEY3(c))] = f2bf(v);
        ctbf[k*NCENT + (c ^ KEY3(k))] = f2bf(v);
        float s = v*v;
        s += __shfl_xor(s, 1);  s += __shfl_xor(s, 2);  s += __shfl_xor(s, 4);
        s += __shfl_xor(s, 8);  s += __shfl_xor(s, 16); s += __shfl_xor(s, 32);
        int w = threadIdx.x >> 6;
        if ((threadIdx.x & 63) == 0) red[w] = s;
        __syncthreads();
        if (threadIdx.x == 0) c2[c] = red[0] + red[1] + red[2] + red[3];
    } else {
        int o = bid - NCENT;       // 0..127 weight rows
        wbf[o*PATCH + (k ^ KEY3(o))] = f2bf(weight[o*PATCH + k]);
    }
}

// ---------------- K0b: x -> flat bf16 (swz KEY3(n)) + x2 (interior float4 fast path) ----------------
__global__ __launch_bounds__(256)
void k0b_flat(const float* __restrict__ x, uint16_t* __restrict__ flat,
              float* __restrict__ x2) {
    int tid = threadIdx.x;
    int w = tid >> 6, lane = tid & 63;
    for (int pp = 0; pp < 8; ++pp) {
        int n = blockIdx.x*32 + pp*4 + w;
        int b = n / LL;
        int rr = n - b*LL;
        int k0 = lane*4;
        int o0 = rr*PATCH + k0;
        int p = o0 / LL; int l = o0 - p*LL;
        int i = l / OHW; int j = l - i*OHW;
        float vals[4];
        {
            int cc = p >> 2, ki = (p >> 1) & 1, kj = p & 1;
            int y = i + ki - 1;
            bool fast = (n < NROWS) && ((unsigned)y < HW) &&
                        (j >= 1 - kj) && (j <= 53 - kj);
            if (fast) {
                f4u v4 = *(const f4u*)(x + ((size_t)(b*CIN + cc)*HW + y)*HW + (j + kj - 1));
                vals[0] = v4.x; vals[1] = v4.y; vals[2] = v4.z; vals[3] = v4.w;
                j += 4;
                if (j >= OHW) { j -= OHW; if (++i == OHW) { i = 0; ++p; } }
            } else {
#pragma unroll
                for (int e = 0; e < 4; ++e) {
                    float val = 0.f;
                    if (n < NROWS) {
                        int cc2 = p >> 2, ki2 = (p >> 1) & 1, kj2 = p & 1;
                        int y2 = i + ki2 - 1, xx = j + kj2 - 1;
                        if ((unsigned)y2 < HW && (unsigned)xx < HW)
                            val = x[((b*CIN + cc2)*HW + y2)*HW + xx];
                    }
                    vals[e] = val;
                    if (++j == OHW) { j = 0; if (++i == OHW) { i = 0; ++p; } }
                }
            }
        }
        float s = 0.f;
        ushort4v pk;
#pragma unroll
        for (int e = 0; e < 4; ++e) {
            pk[e] = f2bf(vals[e]);
            s += vals[e]*vals[e];
        }
        *(ushort4v*)(flat + (size_t)n*PATCH + (k0 ^ KEY3(n))) = pk;
        s += __shfl_xor(s, 1);  s += __shfl_xor(s, 2);  s += __shfl_xor(s, 4);
        s += __shfl_xor(s, 8);  s += __shfl_xor(s, 16); s += __shfl_xor(s, 32);
        if (lane == 0) x2[n] = s;
    }
}

// ---------------- K1: scores GEMM, BK=32, 32KB LDS, 4 blocks/CU, XCD-grouped swizzle ----------------
__global__ __launch_bounds__(256, 4)
void k1_scores(const uint16_t* __restrict__ flat, const uint16_t* __restrict__ cbf,
               const float* __restrict__ x2g, const float* __restrict__ c2g,
               const float* __restrict__ temp_p,
               uint16_t* __restrict__ P, float* __restrict__ denp) {
    __shared__ __align__(16) char lds[32768];   // 2 bufs x (A 8K + B 8K)
    const int tid = threadIdx.x;
    // XCD-grouping swizzle: 4 nt-sharers of one mt get ids === (mod 8) -> same XCD L2
    int id = blockIdx.x + 4*blockIdx.y;         // 0..3251
    int mt, nt;
    if (id < 3232) { mt = (id & 7) + 8*(id >> 5); nt = (id >> 3) & 3; }
    else { int t = id - 3232; mt = 808 + t % 5; nt = t / 5; }   // bijective tail (20)
    const int w = tid >> 6, lane = tid & 63;
    const int wr = w >> 1, wc = w & 1;
    const int l15 = lane & 15, l4 = lane >> 4;

    auto stage = [&](int buf, int kt) {
        const char* srcA = (const char*)flat + (size_t)(mt*128)*512 + kt*64;
        const char* srcB = (const char*)cbf + (size_t)(nt*128)*512 + kt*64;
        char* dA = lds + buf*16384;
        char* dB = dA + 8192;
#pragma unroll
        for (int i = 0; i < 2; ++i) {
            int u = (w*2 + i)*64 + lane;         // 0..511 16B-units
            int row = u >> 2, sub = u & 3;
            gload16(srcA + (size_t)row*512 + sub*16, dA + u*16);
            gload16(srcB + (size_t)row*512 + sub*16, dB + u*16);
        }
    };

    f32x4 acc[4][4];
#pragma unroll
    for (int i = 0; i < 4; ++i)
#pragma unroll
        for (int j = 0; j < 4; ++j) acc[i][j] = (f32x4)0.f;

    stage(0, 0);
    for (int kt = 0; kt < 8; ++kt) {
        __syncthreads();
        if (kt < 7) stage((kt + 1) & 1, kt + 1);
        const char* A = lds + (kt & 1)*16384;
        const char* B = A + 8192;
        short8 af[4], bfm[4];
#pragma unroll
        for (int rf = 0; rf < 4; ++rf) {
            int row = wr*64 + rf*16 + l15;
            int byte = row*64 + ((l4*16) ^ KEY4(row));
            af[rf] = *(const short8*)(A + byte);
        }
#pragma unroll
        for (int cf = 0; cf < 4; ++cf) {
            int row = wc*64 + cf*16 + l15;
            int byte = row*64 + ((l4*16) ^ KEY4(row));
            bfm[cf] = *(const short8*)(B + byte);
        }
#pragma unroll
        for (int rf = 0; rf < 4; ++rf)
#pragma unroll
            for (int cf = 0; cf < 4; ++cf)
                acc[rf][cf] = __builtin_amdgcn_mfma_f32_16x16x32_bf16(
                    af[rf], bfm[cf], acc[rf][cf], 0, 0, 0);
    }

    // epilogue: exp + den partials (fast sqrt via rsq; native exp)
    const float temp = temp_p[0];
    const float ntemp = -temp;
    float c2v[4];
#pragma unroll
    for (int cf = 0; cf < 4; ++cf)
        c2v[cf] = c2g[nt*128 + wc*64 + cf*16 + l15];

    float denacc[4][4];
#pragma unroll
    for (int rf = 0; rf < 4; ++rf) {
#pragma unroll
        for (int rr = 0; rr < 4; ++rr) {
            int n = mt*128 + wr*64 + rf*16 + l4*4 + rr;
            float x2v = x2g[n];
            float d = 0.f;
#pragma unroll
            for (int cf = 0; cf < 4; ++cf) {
                float s = x2v + c2v[cf] - 2.f*acc[rf][cf][rr];
                float sc = fmaxf(s, 1e-12f);
                float dist = sc * __frsqrt_rn(sc);     // sqrt(sc), 1 trans + 1 mul
                float pv = __expf(ntemp * dist);
                acc[rf][cf][rr] = pv;
                d += pv;
            }
            denacc[rf][rr] = d;
        }
    }
#pragma unroll
    for (int rf = 0; rf < 4; ++rf)
#pragma unroll
        for (int rr = 0; rr < 4; ++rr) {
            float v = denacc[rf][rr];
            v += __shfl_xor(v, 1); v += __shfl_xor(v, 2);
            v += __shfl_xor(v, 4); v += __shfl_xor(v, 8);
            if (l15 == 0) {
                int n = mt*128 + wr*64 + rf*16 + l4*4 + rr;
                denp[(size_t)(nt*2 + wc)*NROWS_PAD + n] = v;
            }
        }

    // bounce P through LDS (pre-swizzled KEY3(row) for K2's staging), linear store
    __syncthreads();
    uint16_t* Pl = (uint16_t*)lds;                 // 32KB = 128 x 128 bf16
#pragma unroll
    for (int rf = 0; rf < 4; ++rf)
#pragma unroll
        for (int cf = 0; cf < 4; ++cf)
#pragma unroll
            for (int rr = 0; rr < 4; ++rr) {
                int row = wr*64 + rf*16 + l4*4 + rr;
                int cl  = wc*64 + cf*16 + l15;
                Pl[row*128 + (cl ^ KEY3(row))] = (uint16_t)f2bf(acc[rf][cf][rr]);
            }
    __syncthreads();
#pragma unroll
    for (int i = 0; i < 8; ++i) {
        int c = i*256 + tid;
        int row = c >> 4, sub = c & 15;
        int4v v = *(const int4v*)((const char*)lds + c*16);
        *(int4v*)((char*)P + (size_t)(mt*128 + row)*1024 + nt*256 + sub*16) = v;
    }
}

// ---------------- Kden: den[n] = sum of 8 partials ----------------
__global__ __launch_bounds__(128)
void kden(const float* __restrict__ denp, float* __restrict__ den) {
    int n = blockIdx.x*128 + threadIdx.x;
    float s = 0.f;
#pragma unroll
    for (int p = 0; p < 8; ++p) s += denp[(size_t)p*NROWS_PAD + n];
    den[n] = s;
}

// ---------------- K2: PV GEMM, BK=32, 32KB LDS, 4 blocks/CU, bf16 bounce, XCD-grouped ----------------
__global__ __launch_bounds__(256, 4)
void k2_pv(const uint16_t* __restrict__ P, const uint16_t* __restrict__ ctbf,
           const uint16_t* __restrict__ flat, const float* __restrict__ den,
           const float* __restrict__ temp_p, uint16_t* __restrict__ fbm) {
    __shared__ __align__(16) char lds[32768];   // 2 bufs x (A 8K + B 8K); reused as Tl
    const int tid = threadIdx.x;
    // XCD-grouping swizzle: 2 nt-sharers of one mt -> same XCD L2
    int id = blockIdx.x + 2*blockIdx.y;         // 0..1625
    int mt, nt;
    if (id < 1616) { mt = (id & 7) + 8*(id >> 4); nt = (id >> 3) & 1; }
    else { int t = id - 1616; mt = 808 + t % 5; nt = t / 5; }   // bijective tail (10)
    const int w = tid >> 6, lane = tid & 63;
    const int wr = w >> 1, wc = w & 1;
    const int l15 = lane & 15, l4 = lane >> 4;

    auto stage = [&](int buf, int kt) {
        const char* srcA = (const char*)P + (size_t)(mt*128)*1024 + kt*64;
        const char* srcB = (const char*)ctbf + (size_t)(nt*128)*1024 + kt*64;
        char* dA = lds + buf*16384;
        char* dB = dA + 8192;
#pragma unroll
        for (int i = 0; i < 2; ++i) {
            int u = (w*2 + i)*64 + lane;         // 0..511 16B-units
            int row = u >> 2, sub = u & 3;
            gload16(srcA + (size_t)row*1024 + sub*16, dA + u*16);
            gload16(srcB + (size_t)row*1024 + sub*16, dB + u*16);
        }
    };

    f32x4 acc[4][4];
#pragma unroll
    for (int i = 0; i < 4; ++i)
#pragma unroll
        for (int j = 0; j < 4; ++j) acc[i][j] = (f32x4)0.f;

    stage(0, 0);
    for (int kt = 0; kt < 16; ++kt) {
        __syncthreads();
        if (kt < 15) stage((kt + 1) & 1, kt + 1);
        const char* A = lds + (kt & 1)*16384;
        const char* B = A + 8192;
        short8 af[4], bfm[4];
#pragma unroll
        for (int rf = 0; rf < 4; ++rf) {
            int row = wr*64 + rf*16 + l15;
            int byte = row*64 + ((l4*16) ^ KEY4(row));
            af[rf] = *(const short8*)(A + byte);
        }
#pragma unroll
        for (int cf = 0; cf < 4; ++cf) {
            int row = wc*64 + cf*16 + l15;
            int byte = row*64 + ((l4*16) ^ KEY4(row));
            bfm[cf] = *(const short8*)(B + byte);
        }
#pragma unroll
        for (int rf = 0; rf < 4; ++rf)
#pragma unroll
            for (int cf = 0; cf < 4; ++cf)
                acc[rf][cf] = __builtin_amdgcn_mfma_f32_16x16x32_bf16(
                    af[rf], bfm[cf], acc[rf][cf], 0, 0, 0);
    }

    // preload den for this thread's finalize rows (hide latency under the bounce)
    const float temp = temp_p[0];
    const float inv = 1.f / (temp + 1.f);
    const float tinv = temp * inv;
    float a1r[8];
#pragma unroll
    for (int i = 0; i < 8; ++i) {
        int row = (tid >> 4) + i*16;
        a1r[i] = den[mt*128 + row];
    }

    // ---- bounce acc (bf16, swizzled key row&7) to LDS
    __syncthreads();
    uint16_t* Tl = (uint16_t*)lds;               // 128 x 128 bf16 = 32KB
#pragma unroll
    for (int rf = 0; rf < 4; ++rf)
#pragma unroll
        for (int cf = 0; cf < 4; ++cf)
#pragma unroll
            for (int rr = 0; rr < 4; ++rr) {
                int row = wr*64 + rf*16 + l4*4 + rr;
                int col = wc*64 + cf*16 + l15;
                Tl[row*128 + (col ^ ((row & 7) << 3))] = (uint16_t)f2bf(acc[rf][cf][rr]);
            }
    __syncthreads();

    // ---- coalesced finalize: 8-m chunks, b128 loads/stores, incremental mask
#pragma unroll
    for (int i = 0; i < 8; ++i) {
        int ch = i*256 + tid;
        int row = ch >> 4, m0 = (ch & 15)*8;
        int n = mt*128 + row;
        if (n >= NROWS) continue;
        int m = nt*128 + m0;
        float a1 = __fdividef(tinv, a1r[i]);
        ushort8 tvv = *(const ushort8*)(Tl + row*128 + (m0 ^ ((row & 7) << 3)));
        ushort8 fl = *(const ushort8*)(flat + (size_t)n*PATCH + (m ^ KEY3(row)));
        int b = n / LL;
        int rrow = n - b*LL;
        int o = rrow*PATCH + m;
        int p = o / LL; int l = o - p*LL;
        int ii = l / OHW; int jj = l - ii*OHW;
        ushort8 outv;
#pragma unroll
        for (int e = 0; e < 8; ++e) {
            int ki = (p >> 1) & 1, kj = p & 1;
            bool bad = (ii == 0 && ki == 0) || (ii == 56 && ki == 1) ||
                       (jj == 0 && kj == 0) || (jj == 56 && kj == 1);
            float fin = a1*bf2f(tvv[e]) + bf2f(fl[e])*inv;
            outv[e] = bad ? (unsigned short)0 : f2bf(fin);
            if (++jj == OHW) { jj = 0; if (++ii == OHW) { ii = 0; ++p; } }
        }
        *(ushort8*)(fbm + (size_t)n*PATCH + m) = outv;
    }
}

// ---------------- K4: conv GEMM BK=32, 32KB LDS, 4 blocks/CU ----------------
__global__ __launch_bounds__(256, 4)
void k4_conv(const uint16_t* __restrict__ wbf, const uint16_t* __restrict__ fbm,
             const float* __restrict__ bias, float* __restrict__ out) {
    __shared__ __align__(16) char lds[32768];   // 2 bufs x (A 8K + B 8K); reused f32 bounce
    const int tid = threadIdx.x;
    const int lt = blockIdx.x;     // l-tile 0..25
    const int bb = blockIdx.y;     // batch
    const int w = tid >> 6, lane = tid & 63;
    const int wr = w >> 1, wc = w & 1;
    const int l15 = lane & 15, l4 = lane >> 4;

    auto stageA = [&](int buf, int kt) {
        const char* srcA = (const char*)wbf + kt*64;      // 32 p x 2B
        char* dA = lds + buf*16384;
#pragma unroll
        for (int i = 0; i < 2; ++i) {
            int u = i*256 + tid;                          // 512 units (128 oc x 4)
            int row = u >> 2, sub = u & 3;
            gload16(srcA + (size_t)row*512 + sub*16, dA + u*16);
        }
    };
    // B: transpose-stage fbm[p][l] -> sB[l][p] (32 p per kt, swizzle KEY3(llocal))
    auto stageB = [&](int buf, int kt) {
        uint16_t* sB = (uint16_t*)(lds + buf*16384 + 8192);
        int pl = lane & 31;
        int lh = lane >> 5;
#pragma unroll
        for (int i = 0; i < 2; ++i) {
            int l8 = i*8 + w*2 + lh;                      // 0..15
            const uint16_t* g = fbm + (size_t)bb*PL + (size_t)(kt*32 + pl)*LL + lt*128 + l8*8;
            ushort8u v = *(const ushort8u*)g;             // 16B vector load
#pragma unroll
            for (int e = 0; e < 8; ++e) {
                int llocal = l8*8 + e;
                sB[llocal*32 + (pl ^ KEY3(llocal))] = v[e];
            }
        }
    };

    f32x4 acc[4][4];
#pragma unroll
    for (int i = 0; i < 4; ++i)
#pragma unroll
        for (int j = 0; j < 4; ++j) acc[i][j] = (f32x4)0.f;

    stageA(0, 0); stageB(0, 0);
    for (int kt = 0; kt < 8; ++kt) {
        __syncthreads();
        if (kt < 7) { stageA((kt + 1) & 1, kt + 1); stageB((kt + 1) & 1, kt + 1); }
        const char* A = lds + (kt & 1)*16384;
        const char* B = A + 8192;
        short8 af[4], bfm[4];
#pragma unroll
        for (int rf = 0; rf < 4; ++rf) {
            int row = wr*64 + rf*16 + l15;
            int byte = row*64 + ((l4*16) ^ KEY4(row));
            af[rf] = *(const short8*)(A + byte);
        }
#pragma unroll
        for (int cf = 0; cf < 4; ++cf) {
            int row = wc*64 + cf*16 + l15;
            int byte = row*64 + ((l4*16) ^ KEY4(row));
            bfm[cf] = *(const short8*)(B + byte);
        }
#pragma unroll
        for (int rf = 0; rf < 4; ++rf)
#pragma unroll
            for (int cf = 0; cf < 4; ++cf)
                acc[rf][cf] = __builtin_amdgcn_mfma_f32_16x16x32_bf16(
                    af[rf], bfm[cf], acc[rf][cf], 0, 0, 0);
    }

    // ---- epilogue in two 64-row halves (32KB f32 bounce each)
    float bv[4][4];
#pragma unroll
    for (int rf = 0; rf < 4; ++rf)
#pragma unroll
        for (int rr = 0; rr < 4; ++rr)
            bv[rf][rr] = bias[wr*64 + rf*16 + l4*4 + rr];

    float* Ol = (float*)lds;
    for (int half = 0; half < 2; ++half) {
        __syncthreads();
        if (wr == half) {
#pragma unroll
            for (int rf = 0; rf < 4; ++rf)
#pragma unroll
                for (int cf = 0; cf < 4; ++cf)
#pragma unroll
                    for (int rr = 0; rr < 4; ++rr) {
                        int rowl = rf*16 + l4*4 + rr;     // 0..63
                        int col = wc*64 + cf*16 + l15;
                        Ol[rowl*128 + col] = acc[rf][cf][rr] + bv[rf][rr];
                    }
        }
        __syncthreads();
        int base_oc = half*64;
        if (lt < 25) {
#pragma unroll
            for (int i = 0; i < 8; ++i) {
                int c = i*256 + tid;                      // 2048 units = 64 rows x 32
                int row = c >> 5, sub = c & 31;
                int4u v = *(const int4u*)((const char*)lds + c*16);
                *(int4u*)((char*)out + ((size_t)(bb*OC + base_oc + row)*LL + lt*128 + sub*4)*4) = v;
            }
        } else {
#pragma unroll
            for (int i = 0; i < 8; ++i) {
                int c = i*256 + tid;
                int row = c >> 5, sub = c & 31;
                const float* vp = (const float*)((const char*)lds + c*16);
#pragma unroll
                for (int e = 0; e < 4; ++e) {
                    int l = lt*128 + sub*4 + e;
                    if (l < LL) out[(size_t)(bb*OC + base_oc + row)*LL + l] = vp[e];
                }
            }
        }
    }
}

extern "C" void kernel_launch(void* const* d_in, const int* in_sizes, int n_in,
                              void* d_out, int out_size, void* d_ws, size_t ws_size,
                              hipStream_t stream) {
    const float* x       = (const float*)d_in[0];
    const float* weight  = (const float*)d_in[1];
    const float* bias    = (const float*)d_in[2];
    const float* centers = (const float*)d_in[3];
    const float* temp    = (const float*)d_in[4];
    float* out = (float*)d_out;

    char* ws = (char*)d_ws;
    float*    c2   = (float*)(ws + OFF_C2);
    float*    x2   = (float*)(ws + OFF_X2);
    float*    denp = (float*)(ws + OFF_DENP);
    float*    den  = (float*)(ws + OFF_DEN);
    uint16_t* cbf  = (uint16_t*)(ws + OFF_CBF);
    uint16_t* ctbf = (uint16_t*)(ws + OFF_CTBF);
    uint16_t* wbf  = (uint16_t*)(ws + OFF_WBF);
    uint16_t* flat = (uint16_t*)(ws + OFF_FLAT);
    uint16_t* P    = (uint16_t*)(ws + OFF_P);
    uint16_t* fbm  = (uint16_t*)(ws + OFF_FBM);

    k0a_prep<<<NCENT + OC, 256, 0, stream>>>(centers, weight, cbf, ctbf, wbf, c2);
    k0b_flat<<<NROWS_PAD/32, 256, 0, stream>>>(x, flat, x2);
    k1_scores<<<dim3(4, NROWS_PAD/128), 256, 0, stream>>>(flat, cbf, x2, c2, temp, P, denp);
    kden<<<NROWS_PAD/128, 128, 0, stream>>>(denp, den);
    k2_pv<<<dim3(2, NROWS_PAD/128), 256, 0, stream>>>(P, ctbf, flat, den, temp, fbm);
    k4_conv<<<dim3(26, NB), 256, 0, stream>>>(wbf, fbm, bias, out);
}